// Round 2
// baseline (1747.315 us; speedup 1.0000x reference)
//
#include <hip/hip_runtime.h>
#include <hip/hip_bf16.h>

// Problem constants
#define NETSZ 500
#define DDIM  10
#define NBAT  32
#define TSTEP 8
#define MM    256          // TSTEP*NBAT rows, all timesteps batched

typedef __attribute__((ext_vector_type(8)))  short bhalf8;   // 8 bf16 (as i16) = 4 VGPR
typedef __attribute__((ext_vector_type(16))) float f32x16;

union Frag { bhalf8 v; uint2 q[2]; };

__device__ __forceinline__ unsigned short f2bf(float f) {
    unsigned u = __float_as_uint(f);
    u += 0x7FFFu + ((u >> 16) & 1u);      // round-to-nearest-even
    return (unsigned short)(u >> 16);
}
__device__ __forceinline__ float bf2f(unsigned short h) {
    return __uint_as_float(((unsigned)h) << 16);
}
__device__ __forceinline__ float sigfast(float z) {
    // sigmoid(z) = 1/(1+exp(-z));  exp(-z) = exp2(-z*log2(e))
    float e = __builtin_amdgcn_exp2f(-1.44269504f * z);
    return __builtin_amdgcn_rcpf(1.0f + e);
}

// ---------------- init: build u_all[256][10] from x[N][D][T], init minmax ----
__global__ void initk(const float* __restrict__ x, float* __restrict__ u,
                      unsigned int* __restrict__ mnmx) {
    int gid = blockIdx.x * 256 + threadIdx.x;
    if (gid < MM * DDIM) {
        int m = gid / DDIM, d = gid % DDIM;
        int t = m >> 5, n = m & 31;
        u[gid] = x[n * (DDIM * TSTEP) + d * TSTEP + t];
    } else if (gid < MM * DDIM + 32) {
        int j = gid - MM * DDIM;
        mnmx[j] = ((j & 15) < 8) ? 0x7F800000u : 0u;   // mn=+inf, mx=0
    }
}

// ---------------- first-layer MLPs (K=10, trivial) ---------------------------
__global__ void mlp0(const float* __restrict__ u,
                     const float* __restrict__ W1, const float* __restrict__ b1,
                     const float* __restrict__ Wn1, const float* __restrict__ bn1,
                     float* __restrict__ h1, float* __restrict__ g1) {
    int gid = blockIdx.x * 256 + threadIdx.x;   // 256*300 + 256*500
    if (gid < MM * 300) {
        int m = gid / 300, p = gid % 300;
        float s = b1[p];
        const float* ur = u + m * DDIM; const float* wr = W1 + p * DDIM;
        #pragma unroll
        for (int d = 0; d < DDIM; ++d) s += ur[d] * wr[d];
        h1[gid] = fmaxf(s, 0.0f);
    } else {
        int g = gid - MM * 300;
        int m = g / NETSZ, p = g % NETSZ;
        float s = bn1[p];
        const float* ur = u + m * DDIM; const float* wr = Wn1 + p * DDIM;
        #pragma unroll
        for (int d = 0; d < DDIM; ++d) s += ur[d] * wr[d];
        g1[g] = fmaxf(s, 0.0f);
    }
}

// ---------------- fp32 -> bf16 hi/lo split (with zero k-padding) -------------
__global__ void splitk(const float* __restrict__ src, const int w,
                       unsigned short* __restrict__ dh, unsigned short* __restrict__ dl,
                       const int wp) {
    int gid = blockIdx.x * 256 + threadIdx.x;
    if (gid >= MM * wp) return;
    int m = gid / wp, c = gid % wp;
    float v = (c < w) ? src[m * w + c] : 0.0f;
    unsigned short h = f2bf(v);
    dh[gid] = h;
    dl[gid] = f2bf(v - bf2f(h));
}

// ---------------- bf16x3 MFMA GEMM:  out[256][N] = relu(A[256][K] @ B[N][K]^T + bias)
// A pre-split hi/lo bf16 [256][Kpad]; B fp32 row-major [Nreal][Kreal], converted on the fly.
// Optional fused per-timestep min/max atomics (uint-ordered, values >= 0 post-relu).
#define LDA 36
#define LDB 36
__global__ __launch_bounds__(256, 2)
void gemm_bf16x3(const unsigned short* __restrict__ Ah,
                 const unsigned short* __restrict__ Al,
                 const int Kpad,
                 const float* __restrict__ B, const int Kreal, const int Nreal,
                 const float* __restrict__ bias,
                 float* __restrict__ out, const int ldout,
                 unsigned int* __restrict__ mnmx) {
    __shared__ unsigned short lAh[MM * LDA], lAl[MM * LDA];
    __shared__ unsigned short lBh[128 * LDB], lBl[128 * LDB];

    const int tid = threadIdx.x;
    const int lane = tid & 63;
    const int w   = tid >> 6;            // 0..3
    const int wr  = w >> 1, wc = w & 1;  // m-half, n-half
    const int l31 = lane & 31, l5 = lane >> 5;
    const int r0  = blockIdx.x * 128;

    f32x16 acc[4][2];
    #pragma unroll
    for (int a = 0; a < 4; ++a)
        #pragma unroll
        for (int b = 0; b < 2; ++b)
            #pragma unroll
            for (int j = 0; j < 16; ++j) acc[a][b][j] = 0.0f;

    const int rB = r0 + (tid >> 1);
    const bool rowok = rB < Nreal;
    const int khalf = (tid & 1) * 16;

    for (int k0 = 0; k0 < Kpad; k0 += 32) {
        // stage A: thread tid owns row tid, copies 32 bf16 per half
        {
            const uint4* ga = (const uint4*)(Ah + (size_t)tid * Kpad + k0);
            const uint4* gb = (const uint4*)(Al + (size_t)tid * Kpad + k0);
            uint4 A0 = ga[0], A1 = ga[1], A2 = ga[2], A3 = ga[3];
            uint4 B0 = gb[0], B1 = gb[1], B2 = gb[2], B3 = gb[3];
            uint2* dh = (uint2*)&lAh[tid * LDA];
            uint2* dl = (uint2*)&lAl[tid * LDA];
            dh[0] = make_uint2(A0.x, A0.y); dh[1] = make_uint2(A0.z, A0.w);
            dh[2] = make_uint2(A1.x, A1.y); dh[3] = make_uint2(A1.z, A1.w);
            dh[4] = make_uint2(A2.x, A2.y); dh[5] = make_uint2(A2.z, A2.w);
            dh[6] = make_uint2(A3.x, A3.y); dh[7] = make_uint2(A3.z, A3.w);
            dl[0] = make_uint2(B0.x, B0.y); dl[1] = make_uint2(B0.z, B0.w);
            dl[2] = make_uint2(B1.x, B1.y); dl[3] = make_uint2(B1.z, B1.w);
            dl[4] = make_uint2(B2.x, B2.y); dl[5] = make_uint2(B2.z, B2.w);
            dl[6] = make_uint2(B3.x, B3.y); dl[7] = make_uint2(B3.z, B3.w);
        }
        // stage B: 2 threads per row; fp32 -> bf16 hi/lo in regs -> LDS
        {
            const float* src = B + (size_t)rB * Kreal + k0 + khalf;
            uint2* dh = (uint2*)&lBh[(tid >> 1) * LDB + khalf];
            uint2* dl = (uint2*)&lBl[(tid >> 1) * LDB + khalf];
            #pragma unroll
            for (int c = 0; c < 4; ++c) {
                int k = k0 + khalf + c * 4;
                float4 f = make_float4(0.f, 0.f, 0.f, 0.f);
                if (rowok && k < Kreal) f = *(const float4*)(src + c * 4);
                unsigned short h0 = f2bf(f.x), h1 = f2bf(f.y), h2 = f2bf(f.z), h3 = f2bf(f.w);
                unsigned short q0 = f2bf(f.x - bf2f(h0)), q1 = f2bf(f.y - bf2f(h1));
                unsigned short q2 = f2bf(f.z - bf2f(h2)), q3 = f2bf(f.w - bf2f(h3));
                dh[c] = make_uint2((unsigned)h0 | ((unsigned)h1 << 16),
                                   (unsigned)h2 | ((unsigned)h3 << 16));
                dl[c] = make_uint2((unsigned)q0 | ((unsigned)q1 << 16),
                                   (unsigned)q2 | ((unsigned)q3 << 16));
            }
        }
        __syncthreads();

        #pragma unroll
        for (int ks = 0; ks < 2; ++ks) {
            const int kk = ks * 16 + l5 * 8;   // element offset within 32-k tile
            Frag bh[2], bl[2];
            #pragma unroll
            for (int nt = 0; nt < 2; ++nt) {
                const uint2* ph = (const uint2*)&lBh[(wc * 64 + nt * 32 + l31) * LDB + kk];
                const uint2* pl = (const uint2*)&lBl[(wc * 64 + nt * 32 + l31) * LDB + kk];
                bh[nt].q[0] = ph[0]; bh[nt].q[1] = ph[1];
                bl[nt].q[0] = pl[0]; bl[nt].q[1] = pl[1];
            }
            #pragma unroll
            for (int mt = 0; mt < 4; ++mt) {
                Frag ah, al;
                const uint2* pa = (const uint2*)&lAh[(wr * 128 + mt * 32 + l31) * LDA + kk];
                const uint2* pb = (const uint2*)&lAl[(wr * 128 + mt * 32 + l31) * LDA + kk];
                ah.q[0] = pa[0]; ah.q[1] = pa[1];
                al.q[0] = pb[0]; al.q[1] = pb[1];
                #pragma unroll
                for (int nt = 0; nt < 2; ++nt) {
                    acc[mt][nt] = __builtin_amdgcn_mfma_f32_32x32x16_bf16(ah.v, bh[nt].v, acc[mt][nt], 0, 0, 0);
                    acc[mt][nt] = __builtin_amdgcn_mfma_f32_32x32x16_bf16(ah.v, bl[nt].v, acc[mt][nt], 0, 0, 0);
                    acc[mt][nt] = __builtin_amdgcn_mfma_f32_32x32x16_bf16(al.v, bh[nt].v, acc[mt][nt], 0, 0, 0);
                }
            }
        }
        __syncthreads();
    }

    // epilogue: bias + relu + store + fused per-timestep min/max
    #pragma unroll
    for (int mt = 0; mt < 4; ++mt) {
        float mn = __uint_as_float(0x7F800000u), mx = 0.0f;
        #pragma unroll
        for (int nt = 0; nt < 2; ++nt) {
            const int col = r0 + wc * 64 + nt * 32 + l31;
            const bool ok = col < Nreal;
            const float bs = ok ? bias[col] : 0.0f;
            const int rbase = wr * 128 + mt * 32 + 4 * l5;
            #pragma unroll
            for (int reg = 0; reg < 16; ++reg) {
                const int row = rbase + (reg & 3) + 8 * (reg >> 2);
                float vv = fmaxf(acc[mt][nt][reg] + bs, 0.0f);
                if (ok) {
                    out[(size_t)row * ldout + col] = vv;
                    mn = fminf(mn, vv); mx = fmaxf(mx, vv);
                }
            }
        }
        if (mnmx) {
            #pragma unroll
            for (int o = 32; o; o >>= 1) {
                mn = fminf(mn, __shfl_xor(mn, o));
                mx = fmaxf(mx, __shfl_xor(mx, o));
            }
            if (lane == 0) {
                const int t = wr * 4 + mt;        // rows mt*32.. within wr-half => one timestep
                atomicMin(&mnmx[t],     __float_as_uint(mn));
                atomicMax(&mnmx[8 + t], __float_as_uint(mx));
            }
        }
    }
}

// ---------------- x_bias[m][i] = sum_d gate(a_in[m, i*10+d]) * W_in[i,d] * u[m,d]
__global__ void xbiask(const float* __restrict__ a_in, const float* __restrict__ W_in,
                       const float* __restrict__ u, const unsigned int* __restrict__ mnmx,
                       float* __restrict__ xb) {
    int gid = blockIdx.x * 256 + threadIdx.x;    // 256*500
    int m = gid / NETSZ, i = gid % NETSZ;
    int t = m >> 5;
    float mn = __uint_as_float(mnmx[t]);
    float mx = __uint_as_float(mnmx[8 + t]);
    float sc = 100.0f / (mx - mn);
    float off = fmaf(-mn, sc, -50.0f);
    float s = 0.0f;
    const float* ar = a_in + (size_t)m * (NETSZ * DDIM) + i * DDIM;
    const float* wr = W_in + i * DDIM;
    const float* ur = u + m * DDIM;
    #pragma unroll
    for (int d = 0; d < DDIM; ++d)
        s += sigfast(fmaf(ar[d], sc, off)) * wr[d] * ur[d];
    xb[gid] = s;
}

// ---------------- gated matvec: s_out = relu( (gate(a_net)*W_net) @ v + x_bias )
__global__ __launch_bounds__(256)
void matvec(const float* __restrict__ a_net, const float* __restrict__ Wn,
            const float* __restrict__ v, const int vsel,
            const float* __restrict__ xb, const unsigned int* __restrict__ mnmx,
            float* __restrict__ sout) {
    const int lane = threadIdx.x & 63;
    const int gw = blockIdx.x * 4 + (threadIdx.x >> 6);
    const int i = gw >> 8;        // 0..499  (same i across block -> W row L1-shared)
    const int m = gw & 255;
    const int t = m >> 5;
    const float mn = __uint_as_float(mnmx[t]);
    const float mx = __uint_as_float(mnmx[8 + t]);
    const float sc = 100.0f / (mx - mn);
    const float off = fmaf(-mn, sc, -50.0f);
    const float* arow = a_net + (size_t)m * 250000 + (size_t)i * NETSZ;
    const float* wrow = Wn + (size_t)i * NETSZ;
    const float* vrow = v + (size_t)(vsel ? m : (m & 31)) * NETSZ;
    float sum = 0.0f;
    #pragma unroll
    for (int it = 0; it < 2; ++it) {
        int q = it * 64 + lane;                 // 125 float4 = 500 floats
        if (q < 125) {
            float4 a  = *(const float4*)(arow + q * 4);
            float4 ww = *(const float4*)(wrow + q * 4);
            float4 vv = *(const float4*)(vrow + q * 4);
            sum += sigfast(fmaf(a.x, sc, off)) * ww.x * vv.x;
            sum += sigfast(fmaf(a.y, sc, off)) * ww.y * vv.y;
            sum += sigfast(fmaf(a.z, sc, off)) * ww.z * vv.z;
            sum += sigfast(fmaf(a.w, sc, off)) * ww.w * vv.w;
        }
    }
    #pragma unroll
    for (int o = 32; o; o >>= 1) sum += __shfl_xor(sum, o);
    if (lane == 0)
        sout[(size_t)m * NETSZ + i] = fmaxf(sum + xb[m * NETSZ + i], 0.0f);
}

// ---------------- out[n][d][t] = sum_i s2[t*32+n][i] * Wo[d][i] + bo[d] -------
__global__ void outk(const float* __restrict__ s2, const float* __restrict__ Wo,
                     const float* __restrict__ bo, float* __restrict__ out) {
    int gid = blockIdx.x * 256 + threadIdx.x;   // 32*10*8 = 2560
    int n = gid / (DDIM * TSTEP);
    int r = gid % (DDIM * TSTEP);
    int d = r >> 3, t = r & 7;
    int m = t * 32 + n;
    float s = bo[d];
    const float* sr = s2 + (size_t)m * NETSZ;
    const float* wrp = Wo + (size_t)d * NETSZ;
    for (int k = 0; k < NETSZ; ++k) s += sr[k] * wrp[k];
    out[gid] = s;
}

extern "C" void kernel_launch(void* const* d_in, const int* in_sizes, int n_in,
                              void* d_out, int out_size, void* d_ws, size_t ws_size,
                              hipStream_t stream) {
    const float* x    = (const float*)d_in[0];
    const float* st0  = (const float*)d_in[1];
    const float* W1   = (const float*)d_in[2];
    const float* b1   = (const float*)d_in[3];
    const float* W2   = (const float*)d_in[4];
    const float* b2   = (const float*)d_in[5];
    const float* W3   = (const float*)d_in[6];
    const float* b3   = (const float*)d_in[7];
    const float* Wn1  = (const float*)d_in[8];
    const float* bn1  = (const float*)d_in[9];
    const float* Wn2  = (const float*)d_in[10];
    const float* bn2  = (const float*)d_in[11];
    const float* Wn3  = (const float*)d_in[12];
    const float* bn3  = (const float*)d_in[13];
    const float* W_in = (const float*)d_in[14];
    const float* W_net= (const float*)d_in[15];
    const float* Wo   = (const float*)d_in[16];
    const float* bo   = (const float*)d_in[17];
    float* out = (float*)d_out;

    char* base = (char*)d_ws;
    size_t off = 0;
    auto alloc = [&](size_t bytes) -> void* {
        void* r = base + off;
        off = (off + bytes + 255) & ~(size_t)255;
        return r;
    };
    float* u    = (float*)alloc((size_t)MM * DDIM * 4);
    float* h1   = (float*)alloc((size_t)MM * 300 * 4);
    float* g1   = (float*)alloc((size_t)MM * NETSZ * 4);
    float* h2   = (float*)alloc((size_t)MM * 300 * 4);
    float* g2   = (float*)alloc((size_t)MM * NETSZ * 4);
    unsigned short* h1h = (unsigned short*)alloc((size_t)MM * 320 * 2);
    unsigned short* h1l = (unsigned short*)alloc((size_t)MM * 320 * 2);
    unsigned short* g1h = (unsigned short*)alloc((size_t)MM * 512 * 2);
    unsigned short* g1l = (unsigned short*)alloc((size_t)MM * 512 * 2);
    unsigned short* h2h = (unsigned short*)alloc((size_t)MM * 320 * 2);
    unsigned short* h2l = (unsigned short*)alloc((size_t)MM * 320 * 2);
    unsigned short* g2h = (unsigned short*)alloc((size_t)MM * 512 * 2);
    unsigned short* g2l = (unsigned short*)alloc((size_t)MM * 512 * 2);
    float* a_in = (float*)alloc((size_t)MM * NETSZ * DDIM * 4);
    float* xb   = (float*)alloc((size_t)MM * NETSZ * 4);
    float* s1   = (float*)alloc((size_t)MM * NETSZ * 4);
    float* s2   = (float*)alloc((size_t)MM * NETSZ * 4);
    unsigned int* mnmx = (unsigned int*)alloc(32 * 4);   // [0..16) a_net (mn8,mx8), [16..32) a_in
    float* a_net = (float*)alloc((size_t)MM * NETSZ * NETSZ * 4);   // 256 MB

    if (ws_size < off) return;   // workspace too small: leave output zero (loud, safe fail)

    initk<<<11, 256, 0, stream>>>(x, u, mnmx);
    mlp0<<<800, 256, 0, stream>>>(u, W1, b1, Wn1, bn1, h1, g1);
    splitk<<<320, 256, 0, stream>>>(h1, 300, h1h, h1l, 320);
    splitk<<<512, 256, 0, stream>>>(g1, NETSZ, g1h, g1l, 512);
    gemm_bf16x3<<<3, 256, 0, stream>>>(h1h, h1l, 320, W2, 300, 300, b2, h2, 300, nullptr);
    splitk<<<320, 256, 0, stream>>>(h2, 300, h2h, h2l, 320);
    gemm_bf16x3<<<4, 256, 0, stream>>>(g1h, g1l, 512, Wn2, NETSZ, NETSZ, bn2, g2, NETSZ, nullptr);
    splitk<<<512, 256, 0, stream>>>(g2, NETSZ, g2h, g2l, 512);
    gemm_bf16x3<<<40, 256, 0, stream>>>(h2h, h2l, 320, W3, 300, NETSZ * DDIM, b3, a_in, NETSZ * DDIM, mnmx + 16);
    gemm_bf16x3<<<1954, 256, 0, stream>>>(g2h, g2l, 512, Wn3, NETSZ, NETSZ * NETSZ, bn3, a_net, NETSZ * NETSZ, mnmx);
    xbiask<<<500, 256, 0, stream>>>(a_in, W_in, u, mnmx + 16, xb);
    matvec<<<32000, 256, 0, stream>>>(a_net, W_net, st0, 0, xb, mnmx, s1);
    matvec<<<32000, 256, 0, stream>>>(a_net, W_net, s1, 1, xb, mnmx, s2);
    outk<<<10, 256, 0, stream>>>(s2, Wo, bo, out);
}